// Round 10
// baseline (688.808 us; speedup 1.0000x reference)
//
#include <hip/hip_runtime.h>
#include <math.h>

// ============ DIAGNOSTIC ROUND: grids x16, block index folded. ============
// Kernel bodies identical to R9 (67.0 us). dur/16 = per-kernel cost; counters
// become visible in rocprof top-5 (harness memsets are ~45 us).
#define AMP 16

#define NPIX 16384
#define CC 256
#define OFFW 144
#define MSKW 72

typedef unsigned short ushortT;
typedef __attribute__((ext_vector_type(4))) float f32x4;
typedef __attribute__((ext_vector_type(8))) __bf16 bf16x8;
typedef __attribute__((ext_vector_type(8))) unsigned short u16x8;
typedef __attribute__((ext_vector_type(4))) unsigned int u32x4;

__device__ __forceinline__ float bf2f(ushortT u) {
    union { unsigned u; float f; } x; x.u = ((unsigned)u) << 16; return x.f;
}
__device__ __forceinline__ ushortT f2bf(float f) {
    union { float f; unsigned u; } x; x.f = f;
    unsigned u = x.u;
    return (ushortT)((u + 0x7FFFu + ((u >> 16) & 1u)) >> 16);
}
__device__ __forceinline__ float bflo(unsigned u) { return __uint_as_float(u << 16); }
__device__ __forceinline__ float bfhi(unsigned u) { return __uint_as_float(u & 0xFFFF0000u); }

typedef __attribute__((address_space(3))) char lds_char;
typedef __attribute__((address_space(1))) char glb_char;
__device__ __forceinline__ void gload_lds16(const void* g, void* l) {
    __builtin_amdgcn_global_load_lds((const glb_char*)g, (lds_char*)l, 16, 0, 0);
}

// ---------------- k_wt ----------------
__global__ __launch_bounds__(256) void k_wt(
    const float* __restrict__ W_in, const float* __restrict__ W_out,
    const float* __restrict__ W_off, const float* __restrict__ W_mask,
    const float* __restrict__ b_in, const float* __restrict__ b_out,
    const float* __restrict__ b_off, const float* __restrict__ b_mask,
    ushortT* __restrict__ Wt, float* __restrict__ biasb)
{
    const int idx = (blockIdx.x % 768) * 256 + threadIdx.x;   // AMP fold
    const int slot = idx >> 16;
    const int rem = idx & 65535;
    const int n = rem >> 8, k = rem & 255;
    float v;
    if (slot == 0)      v = W_in[k * 256 + n];
    else if (slot == 1) v = W_out[k * 256 + n];
    else {
        const int g = n >> 5, r = n & 31;
        if (r < 18)      v = W_off[k * OFFW + g * 18 + r];
        else if (r < 27) v = W_mask[k * MSKW + g * 9 + (r - 18)];
        else             v = 0.f;
    }
    Wt[idx] = f2bf(v);
    if (n == 0) {
        float b;
        if (slot == 0)      b = b_in[k];
        else if (slot == 1) b = b_out[k];
        else {
            const int g = k >> 5, r = k & 31;
            b = (r < 18) ? b_off[g * 18 + r] : (r < 27 ? b_mask[g * 9 + (r - 18)] : 0.f);
        }
        biasb[slot * 256 + k] = b;
    }
}

// ---------------- k_fused_in ----------------
__global__ __launch_bounds__(512, 4) void k_fused_in(
    const float* __restrict__ x, const float* __restrict__ dw_w,
    const float* __restrict__ bn_gamma, const float* __restrict__ bn_beta,
    const float* __restrict__ bn_mean, const float* __restrict__ bn_var,
    const ushortT* __restrict__ Wt, const float* __restrict__ biasb,
    ushortT* __restrict__ xpb, ushortT* __restrict__ omb)
{
    __shared__ __align__(16) ushortT xA[32 * 256];
    __shared__ __align__(16) ushortT x1s[32 * 256];
    const int tid = threadIdx.x;
    const int b0 = blockIdx.x & 511;                 // AMP fold
    const int lb = (b0 & 7) * 64 + (b0 >> 3);
    const int base = lb * 32;
    const int n = base >> 12, h = (base >> 6) & 63, bw0 = base & 63;

    const int lane = tid & 63, wave = tid >> 6;
    const int gemm = wave >> 2, wc = wave & 3;
    const ushortT* Bt = Wt + (gemm ? 2 * 65536 : 0);

    {
        const int c = tid & 255, half = tid >> 8;
        float wreg[9];
        #pragma unroll
        for (int k = 0; k < 9; ++k) wreg[k] = dw_w[c * 9 + k];
        const float scale = bn_gamma[c] * rsqrtf(bn_var[c] + 1e-3f);
        const float mean = bn_mean[c], beta = bn_beta[c];
        const bool hv0 = h >= 1, hv2 = h <= 62;
        const float* r0 = x + ((size_t)(n * 64 + h - 1) * 64) * 256 + c;
        const float* r1 = x + ((size_t)(n * 64 + h) * 64) * 256 + c;
        const float* r2 = x + ((size_t)(n * 64 + h + 1) * 64) * 256 + c;
        const int w0 = bw0 + half * 16;
        float a0, a1, a2, e0, e1, e2;
        if (w0 - 1 >= 0) {
            a0 = hv0 ? r0[(w0 - 1) * 256] : 0.f;
            a1 = r1[(w0 - 1) * 256];
            a2 = hv2 ? r2[(w0 - 1) * 256] : 0.f;
        } else { a0 = a1 = a2 = 0.f; }
        e0 = hv0 ? r0[w0 * 256] : 0.f;
        e1 = r1[w0 * 256];
        e2 = hv2 ? r2[w0 * 256] : 0.f;
        #pragma unroll
        for (int i = 0; i < 16; ++i) {
            const int w = w0 + i;
            float d0, d1, d2;
            if (w + 1 < 64) {
                d0 = hv0 ? r0[(w + 1) * 256] : 0.f;
                d1 = r1[(w + 1) * 256];
                d2 = hv2 ? r2[(w + 1) * 256] : 0.f;
            } else { d0 = d1 = d2 = 0.f; }
            const float accv = a0 * wreg[0] + e0 * wreg[1] + d0 * wreg[2]
                             + a1 * wreg[3] + e1 * wreg[4] + d1 * wreg[5]
                             + a2 * wreg[6] + e2 * wreg[7] + d2 * wreg[8];
            const float yv = (accv - mean) * scale + beta;
            const float s = yv / (1.f + __expf(-yv));
            const int row = half * 16 + i;
            const int sb = (row * 512 + c * 2) ^ ((row & 7) << 4);
            *(ushortT*)((char*)x1s + sb) = f2bf(s);
            *(ushortT*)((char*)xA + sb) = f2bf(e1);
            a0 = e0; a1 = e1; a2 = e2;
            e0 = d0; e1 = d1; e2 = d2;
        }
    }

    bf16x8 bbp[4];
    #pragma unroll
    for (int nn = 0; nn < 4; ++nn) {
        const int ncol = wc * 64 + nn * 16 + (lane & 15);
        bbp[nn] = *(const bf16x8*)(Bt + (size_t)ncol * 256 + (lane >> 4) * 8);
    }
    __syncthreads();

    const ushortT* As = gemm ? x1s : xA;
    const float* bias = biasb + (gemm ? 512 : 0);
    ushortT* Cout = gemm ? omb : xpb;

    f32x4 acc[2][4];
    #pragma unroll
    for (int m = 0; m < 2; ++m)
        #pragma unroll
        for (int nn = 0; nn < 4; ++nn) acc[m][nn] = (f32x4){0.f, 0.f, 0.f, 0.f};

    #pragma unroll
    for (int k0 = 0; k0 < 256; k0 += 32) {
        bf16x8 af[2], bb[4];
        #pragma unroll
        for (int nn = 0; nn < 4; ++nn) bb[nn] = bbp[nn];
        if (k0 + 32 < 256) {
            #pragma unroll
            for (int nn = 0; nn < 4; ++nn) {
                const int ncol = wc * 64 + nn * 16 + (lane & 15);
                bbp[nn] = *(const bf16x8*)(Bt + (size_t)ncol * 256 + (k0 + 32) + (lane >> 4) * 8);
            }
        }
        #pragma unroll
        for (int m = 0; m < 2; ++m) {
            const int row = m * 16 + (lane & 15);
            af[m] = *(const bf16x8*)((const char*)As + row * 512 +
                     (((k0 + (lane >> 4) * 8) * 2) ^ ((row & 7) << 4)));
        }
        #pragma unroll
        for (int m = 0; m < 2; ++m)
            #pragma unroll
            for (int nn = 0; nn < 4; ++nn)
                acc[m][nn] = __builtin_amdgcn_mfma_f32_16x16x32_bf16(af[m], bb[nn], acc[m][nn], 0, 0, 0);
    }

    const int rbase = (lane >> 4) * 4, col16 = lane & 15;
    #pragma unroll
    for (int m = 0; m < 2; ++m) {
        #pragma unroll
        for (int nn = 0; nn < 4; ++nn) {
            const int col = wc * 64 + nn * 16 + col16;
            const float bj = bias[col];
            #pragma unroll
            for (int r = 0; r < 4; ++r) {
                const int row = m * 16 + rbase + r;
                Cout[(size_t)(base + row) * 256 + col] = f2bf(acc[m][nn][r] + bj);
            }
        }
    }
}

// ---------------- k_core ----------------
__global__ __launch_bounds__(256) void k_core(
    const ushortT* __restrict__ omb, const ushortT* __restrict__ xpb,
    ushortT* __restrict__ coreb)
{
    __shared__ __align__(16) float wtab[8][72][8];
    const int tid = threadIdx.x;
    const int b0 = blockIdx.x & 2047;                // AMP fold
    const int lb = (b0 & 7) * 256 + (b0 >> 3);
    const int base = lb * 8;
    const int n = base >> 12, h = (base >> 6) & 63, w0 = base & 63;

    if (tid < 64) {
        const int px = tid >> 3, g = tid & 7;
        const ushortT* omp = omb + (size_t)(base + px) * 256 + g * 32;
        const u32x4 L0 = *(const u32x4*)(omp);
        const u32x4 L1 = *(const u32x4*)(omp + 8);
        const u32x4 L2 = *(const u32x4*)(omp + 16);
        const u32x4 L3 = *(const u32x4*)(omp + 24);
        unsigned opair[9];
        #pragma unroll
        for (int p = 0; p < 4; ++p) { opair[p] = L0[p]; opair[4 + p] = L1[p]; }
        opair[8] = L2[0];
        float lg[9];
        lg[0] = bflo(L2[1]); lg[1] = bfhi(L2[1]);
        lg[2] = bflo(L2[2]); lg[3] = bfhi(L2[2]);
        lg[4] = bflo(L2[3]); lg[5] = bfhi(L2[3]);
        lg[6] = bflo(L3[0]); lg[7] = bfhi(L3[0]);
        lg[8] = bflo(L3[1]);
        float mx = -1e30f;
        #pragma unroll
        for (int p = 0; p < 9; ++p) mx = fmaxf(mx, lg[p]);
        float e[9], sum = 0.f;
        #pragma unroll
        for (int p = 0; p < 9; ++p) { e[p] = __expf(lg[p] - mx); sum += e[p]; }
        const float inv = 1.f / sum;
        #pragma unroll
        for (int p = 0; p < 9; ++p) {
            const float m = e[p] * inv;
            const float ox = bflo(opair[p]), oy = bfhi(opair[p]);
            const float pxc = (float)(w0 + px + p / 3) + ox;
            const float pyc = (float)(h + p % 3) + oy;
            const float xf = floorf(pxc), yf = floorf(pyc);
            const float tx = pxc - xf, ty = pyc - yf;
            const int x0 = (int)xf - 1, y0 = (int)yf - 1;
            const int x1 = x0 + 1, y1 = y0 + 1;
            const float wx0 = ((unsigned)x0 < 64u) ? (1.f - tx) : 0.f;
            const float wx1 = ((unsigned)x1 < 64u) ? tx : 0.f;
            const float wy0 = ((unsigned)y0 < 64u) ? (1.f - ty) : 0.f;
            const float wy1 = ((unsigned)y1 < 64u) ? ty : 0.f;
            const int cx0 = min(max(x0, 0), 63), cx1 = min(max(x1, 0), 63);
            const int cy0 = min(max(y0, 0), 63), cy1 = min(max(y1, 0), 63);
            float* dst = wtab[px][g * 9 + p];
            float4 idx4, wt4;
            idx4.x = __int_as_float((cy0 * 64 + cx0) * 256);
            idx4.y = __int_as_float((cy0 * 64 + cx1) * 256);
            idx4.z = __int_as_float((cy1 * 64 + cx0) * 256);
            idx4.w = __int_as_float((cy1 * 64 + cx1) * 256);
            wt4.x = m * wx0 * wy0; wt4.y = m * wx1 * wy0;
            wt4.z = m * wx0 * wy1; wt4.w = m * wx1 * wy1;
            *(float4*)dst = idx4;
            *(float4*)(dst + 4) = wt4;
        }
    }
    __syncthreads();

    const int px = tid >> 5, g = (tid >> 2) & 7, o = tid & 3;
    const ushortT* xn = xpb + (size_t)n * (4096 * 256) + g * 32 + o * 8;
    float acc[8];
    #pragma unroll
    for (int j = 0; j < 8; ++j) acc[j] = 0.f;
    #pragma unroll
    for (int p = 0; p < 9; ++p) {
        const float* wt = wtab[px][g * 9 + p];
        const int4 o4 = *(const int4*)(wt);
        const float4 w4 = *(const float4*)(wt + 4);
        const u32x4 A = *(const u32x4*)(xn + o4.x);
        const u32x4 B = *(const u32x4*)(xn + o4.y);
        const u32x4 C = *(const u32x4*)(xn + o4.z);
        const u32x4 D = *(const u32x4*)(xn + o4.w);
        #pragma unroll
        for (int i = 0; i < 4; ++i) {
            acc[2 * i]     += w4.x * bflo(A[i]) + w4.y * bflo(B[i])
                            + w4.z * bflo(C[i]) + w4.w * bflo(D[i]);
            acc[2 * i + 1] += w4.x * bfhi(A[i]) + w4.y * bfhi(B[i])
                            + w4.z * bfhi(C[i]) + w4.w * bfhi(D[i]);
        }
    }
    u16x8 cv;
    #pragma unroll
    for (int j = 0; j < 8; ++j) cv[j] = f2bf(acc[j]);
    *(u16x8*)(coreb + (size_t)(base + px) * 256 + g * 32 + o * 8) = cv;
}

// ---------------- k_gemm_out ----------------
__global__ __launch_bounds__(512) void k_gemm_out(
    const ushortT* __restrict__ A, const ushortT* __restrict__ Bt,
    const float* __restrict__ bias, float* __restrict__ out)
{
    __shared__ __align__(16) ushortT As[32 * 256];
    const int tid = threadIdx.x;
    const int m0 = (blockIdx.x & 511) * 32;          // AMP fold
    const int lane = tid & 63, wave = tid >> 6;

    #pragma unroll
    for (int it = 0; it < 2; ++it) {
        const int i = it * 512 + tid;
        const int row = i >> 5, ch = i & 31;
        const int sch = ch ^ (row & 7);
        gload_lds16(A + (size_t)(m0 + row) * 256 + sch * 8, (char*)As + i * 16);
    }
    bf16x8 bbp[2];
    #pragma unroll
    for (int nn = 0; nn < 2; ++nn) {
        const int ncol = wave * 32 + nn * 16 + (lane & 15);
        bbp[nn] = *(const bf16x8*)(Bt + (size_t)ncol * 256 + (lane >> 4) * 8);
    }
    asm volatile("s_waitcnt vmcnt(0)");
    __syncthreads();

    f32x4 acc[2][2];
    #pragma unroll
    for (int m = 0; m < 2; ++m)
        #pragma unroll
        for (int nn = 0; nn < 2; ++nn) acc[m][nn] = (f32x4){0.f, 0.f, 0.f, 0.f};

    #pragma unroll
    for (int k0 = 0; k0 < 256; k0 += 32) {
        bf16x8 af[2], bb[2];
        #pragma unroll
        for (int nn = 0; nn < 2; ++nn) bb[nn] = bbp[nn];
        if (k0 + 32 < 256) {
            #pragma unroll
            for (int nn = 0; nn < 2; ++nn) {
                const int ncol = wave * 32 + nn * 16 + (lane & 15);
                bbp[nn] = *(const bf16x8*)(Bt + (size_t)ncol * 256 + (k0 + 32) + (lane >> 4) * 8);
            }
        }
        #pragma unroll
        for (int m = 0; m < 2; ++m) {
            const int row = m * 16 + (lane & 15);
            af[m] = *(const bf16x8*)((const char*)As + row * 512 +
                     (((k0 + (lane >> 4) * 8) * 2) ^ ((row & 7) << 4)));
        }
        #pragma unroll
        for (int m = 0; m < 2; ++m)
            #pragma unroll
            for (int nn = 0; nn < 2; ++nn)
                acc[m][nn] = __builtin_amdgcn_mfma_f32_16x16x32_bf16(af[m], bb[nn], acc[m][nn], 0, 0, 0);
    }

    const int rbase = (lane >> 4) * 4, col16 = lane & 15;
    #pragma unroll
    for (int m = 0; m < 2; ++m) {
        #pragma unroll
        for (int nn = 0; nn < 2; ++nn) {
            const int col = wave * 32 + nn * 16 + col16;
            const float bj = bias[col];
            #pragma unroll
            for (int r = 0; r < 4; ++r) {
                const int row = m0 + m * 16 + rbase + r;
                out[(size_t)row * 256 + col] = acc[m][nn][r] + bj;
            }
        }
    }
}

extern "C" void kernel_launch(void* const* d_in, const int* in_sizes, int n_in,
                              void* d_out, int out_size, void* d_ws, size_t ws_size,
                              hipStream_t stream) {
    const float* x        = (const float*)d_in[0];
    const float* dw_w     = (const float*)d_in[1];
    const float* bn_gamma = (const float*)d_in[2];
    const float* bn_beta  = (const float*)d_in[3];
    const float* bn_mean  = (const float*)d_in[4];
    const float* bn_var   = (const float*)d_in[5];
    const float* W_off    = (const float*)d_in[6];
    const float* b_off    = (const float*)d_in[7];
    const float* W_mask   = (const float*)d_in[8];
    const float* b_mask   = (const float*)d_in[9];
    const float* W_in     = (const float*)d_in[10];
    const float* b_in     = (const float*)d_in[11];
    const float* W_out    = (const float*)d_in[12];
    const float* b_out    = (const float*)d_in[13];
    float* out = (float*)d_out;

    char* w = (char*)d_ws;
    ushortT* Wt    = (ushortT*)w;
    float* biasb   = (float*)(w + 393216);
    ushortT* xpb   = (ushortT*)(w + 396288);
    ushortT* omb   = (ushortT*)(w + 396288 + 8388608);
    ushortT* coreb = (ushortT*)(w + 396288 + 2 * 8388608);

    hipLaunchKernelGGL(k_wt, dim3(768 * AMP), dim3(256), 0, stream,
                       W_in, W_out, W_off, W_mask, b_in, b_out, b_off, b_mask, Wt, biasb);
    hipLaunchKernelGGL(k_fused_in, dim3(512 * AMP), dim3(512), 0, stream,
                       x, dw_w, bn_gamma, bn_beta, bn_mean, bn_var, Wt, biasb, xpb, omb);
    hipLaunchKernelGGL(k_core, dim3(2048 * AMP), dim3(256), 0, stream,
                       omb, xpb, coreb);
    hipLaunchKernelGGL(k_gemm_out, dim3(512 * AMP), dim3(512), 0, stream,
                       coreb, Wt + 65536, biasb + 256, out);
}

// Round 11
// 63.882 us; speedup vs baseline: 10.7824x; 10.7824x over previous
//
#include <hip/hip_runtime.h>
#include <math.h>

#define NPIX 16384
#define CC 256
#define OFFW 144
#define MSKW 72

typedef unsigned short ushortT;
typedef __attribute__((ext_vector_type(4))) float f32x4;
typedef __attribute__((ext_vector_type(8))) __bf16 bf16x8;
typedef __attribute__((ext_vector_type(8))) unsigned short u16x8;
typedef __attribute__((ext_vector_type(4))) unsigned int u32x4;

__device__ __forceinline__ float bf2f(ushortT u) {
    union { unsigned u; float f; } x; x.u = ((unsigned)u) << 16; return x.f;
}
// native RTNE cast (compiler emits v_cvt_*_bf16; pairs into cvt_pk where possible)
__device__ __forceinline__ ushortT f2bf(float f) {
    __bf16 h = (__bf16)f;
    ushortT u;
    __builtin_memcpy(&u, &h, 2);
    return u;
}
__device__ __forceinline__ float bflo(unsigned u) { return __uint_as_float(u << 16); }
__device__ __forceinline__ float bfhi(unsigned u) { return __uint_as_float(u & 0xFFFF0000u); }

typedef __attribute__((address_space(3))) char lds_char;
typedef __attribute__((address_space(1))) char glb_char;
__device__ __forceinline__ void gload_lds16(const void* g, void* l) {
    __builtin_amdgcn_global_load_lds((const glb_char*)g, (lds_char*)l, 16, 0, 0);
}

// ---------------- k_wt: Wt[slot][n][k] = bf16(W[k][n]); bias pad ----------------
// slot 2 (offmask) columns PERMUTED to [g][32]: r<18 offset, 18<=r<27 mask, else 0.
__global__ __launch_bounds__(256) void k_wt(
    const float* __restrict__ W_in, const float* __restrict__ W_out,
    const float* __restrict__ W_off, const float* __restrict__ W_mask,
    const float* __restrict__ b_in, const float* __restrict__ b_out,
    const float* __restrict__ b_off, const float* __restrict__ b_mask,
    ushortT* __restrict__ Wt, float* __restrict__ biasb)
{
    const int idx = blockIdx.x * 256 + threadIdx.x;   // 3*65536 total
    const int slot = idx >> 16;
    const int rem = idx & 65535;
    const int n = rem >> 8, k = rem & 255;
    float v;
    if (slot == 0)      v = W_in[k * 256 + n];
    else if (slot == 1) v = W_out[k * 256 + n];
    else {
        const int g = n >> 5, r = n & 31;
        if (r < 18)      v = W_off[k * OFFW + g * 18 + r];
        else if (r < 27) v = W_mask[k * MSKW + g * 9 + (r - 18)];
        else             v = 0.f;
    }
    Wt[idx] = f2bf(v);
    if (n == 0) {
        float b;
        if (slot == 0)      b = b_in[k];
        else if (slot == 1) b = b_out[k];
        else {
            const int g = k >> 5, r = k & 31;
            b = (r < 18) ? b_off[g * 18 + r] : (r < 27 ? b_mask[g * 9 + (r - 18)] : 0.f);
        }
        biasb[slot * 256 + k] = b;
    }
}

// ---------------- k_fused_in: dwconv+BN+SiLU + xproj GEMM (bf16) + offmask GEMM (bf16) ----------------
// 32 pixels per block, 512 threads, 512 blocks. LDS swizzle: chunk ^= row&15 (conflict-free).
__global__ __launch_bounds__(512, 4) void k_fused_in(
    const float* __restrict__ x, const float* __restrict__ dw_w,
    const float* __restrict__ bn_gamma, const float* __restrict__ bn_beta,
    const float* __restrict__ bn_mean, const float* __restrict__ bn_var,
    const ushortT* __restrict__ Wt, const float* __restrict__ biasb,
    ushortT* __restrict__ xpb, ushortT* __restrict__ omb)
{
    __shared__ __align__(16) ushortT xA[32 * 256];
    __shared__ __align__(16) ushortT x1s[32 * 256];
    const int tid = threadIdx.x;
    const int b0 = blockIdx.x;
    const int lb = (b0 & 7) * 64 + (b0 >> 3);        // XCD-chunked
    const int base = lb * 32;
    const int n = base >> 12, h = (base >> 6) & 63, bw0 = base & 63;

    const int lane = tid & 63, wave = tid >> 6;
    const int gemm = wave >> 2, wc = wave & 3;
    const ushortT* Bt = Wt + (gemm ? 2 * 65536 : 0);

    // dwconv + BN + SiLU; thread = (half, c)
    {
        const int c = tid & 255, half = tid >> 8;
        float wreg[9];
        #pragma unroll
        for (int k = 0; k < 9; ++k) wreg[k] = dw_w[c * 9 + k];
        const float scale = bn_gamma[c] * rsqrtf(bn_var[c] + 1e-3f);
        const float mean = bn_mean[c], beta = bn_beta[c];
        const bool hv0 = h >= 1, hv2 = h <= 62;
        const float* r0 = x + ((size_t)(n * 64 + h - 1) * 64) * 256 + c;
        const float* r1 = x + ((size_t)(n * 64 + h) * 64) * 256 + c;
        const float* r2 = x + ((size_t)(n * 64 + h + 1) * 64) * 256 + c;
        const int w0 = bw0 + half * 16;
        float a0, a1, a2, e0, e1, e2;
        if (w0 - 1 >= 0) {
            a0 = hv0 ? r0[(w0 - 1) * 256] : 0.f;
            a1 = r1[(w0 - 1) * 256];
            a2 = hv2 ? r2[(w0 - 1) * 256] : 0.f;
        } else { a0 = a1 = a2 = 0.f; }
        e0 = hv0 ? r0[w0 * 256] : 0.f;
        e1 = r1[w0 * 256];
        e2 = hv2 ? r2[w0 * 256] : 0.f;
        #pragma unroll
        for (int i = 0; i < 16; ++i) {
            const int w = w0 + i;
            float d0, d1, d2;
            if (w + 1 < 64) {
                d0 = hv0 ? r0[(w + 1) * 256] : 0.f;
                d1 = r1[(w + 1) * 256];
                d2 = hv2 ? r2[(w + 1) * 256] : 0.f;
            } else { d0 = d1 = d2 = 0.f; }
            const float accv = a0 * wreg[0] + e0 * wreg[1] + d0 * wreg[2]
                             + a1 * wreg[3] + e1 * wreg[4] + d1 * wreg[5]
                             + a2 * wreg[6] + e2 * wreg[7] + d2 * wreg[8];
            const float yv = (accv - mean) * scale + beta;
            // SiLU via v_rcp (approx rcp: ~1e-7 rel err, invisible in bf16)
            const float s = yv * __builtin_amdgcn_rcpf(1.f + __expf(-yv));
            const int row = half * 16 + i;
            const int sb = (row * 512 + c * 2) ^ ((row & 15) << 4);
            *(ushortT*)((char*)x1s + sb) = f2bf(s);
            *(ushortT*)((char*)xA + sb) = f2bf(e1);
            a0 = e0; a1 = e1; a2 = e2;
            e0 = d0; e1 = d1; e2 = d2;
        }
    }

    // prefetch B fragments for k0=0 BEFORE the barrier
    bf16x8 bbp[4];
    #pragma unroll
    for (int nn = 0; nn < 4; ++nn) {
        const int ncol = wc * 64 + nn * 16 + (lane & 15);
        bbp[nn] = *(const bf16x8*)(Bt + (size_t)ncol * 256 + (lane >> 4) * 8);
    }
    __syncthreads();

    const ushortT* As = gemm ? x1s : xA;
    const float* bias = biasb + (gemm ? 512 : 0);
    ushortT* Cout = gemm ? omb : xpb;

    f32x4 acc[2][4];
    #pragma unroll
    for (int m = 0; m < 2; ++m)
        #pragma unroll
        for (int nn = 0; nn < 4; ++nn) acc[m][nn] = (f32x4){0.f, 0.f, 0.f, 0.f};

    #pragma unroll
    for (int k0 = 0; k0 < 256; k0 += 32) {
        bf16x8 af[2], bb[4];
        #pragma unroll
        for (int nn = 0; nn < 4; ++nn) bb[nn] = bbp[nn];
        if (k0 + 32 < 256) {
            #pragma unroll
            for (int nn = 0; nn < 4; ++nn) {
                const int ncol = wc * 64 + nn * 16 + (lane & 15);
                bbp[nn] = *(const bf16x8*)(Bt + (size_t)ncol * 256 + (k0 + 32) + (lane >> 4) * 8);
            }
        }
        #pragma unroll
        for (int m = 0; m < 2; ++m) {
            const int row = m * 16 + (lane & 15);
            af[m] = *(const bf16x8*)((const char*)As + row * 512 +
                     (((k0 + (lane >> 4) * 8) * 2) ^ ((row & 15) << 4)));
        }
        #pragma unroll
        for (int m = 0; m < 2; ++m)
            #pragma unroll
            for (int nn = 0; nn < 4; ++nn)
                acc[m][nn] = __builtin_amdgcn_mfma_f32_16x16x32_bf16(af[m], bb[nn], acc[m][nn], 0, 0, 0);
    }

    const int rbase = (lane >> 4) * 4, col16 = lane & 15;
    #pragma unroll
    for (int m = 0; m < 2; ++m) {
        #pragma unroll
        for (int nn = 0; nn < 4; ++nn) {
            const int col = wc * 64 + nn * 16 + col16;
            const float bj = bias[col];
            #pragma unroll
            for (int r = 0; r < 4; ++r) {
                const int row = m * 16 + rbase + r;
                Cout[(size_t)(base + row) * 256 + col] = f2bf(acc[m][nn][r] + bj);
            }
        }
    }
}

// ---------------- k_core: LDS-FREE — inline softmax/taps + bf16 wide gather ----------------
// 8 pixels per block, 256 threads, 2048 blocks. No __syncthreads, no shared mem.
// The 4 'o'-siblings of each (px,g) recompute taps redundantly (~210 VALU) — cheaper
// than the old 64-thread tap phase (75% lanes idle) + barrier + LDS round-trip.
__global__ __launch_bounds__(256) void k_core(
    const ushortT* __restrict__ omb, const ushortT* __restrict__ xpb,
    ushortT* __restrict__ coreb)
{
    const int tid = threadIdx.x;
    const int b0 = blockIdx.x;
    const int lb = (b0 & 7) * 256 + (b0 >> 3);        // XCD-chunked
    const int base = lb * 8;
    const int n = base >> 12, h = (base >> 6) & 63, w0 = base & 63;

    const int px = tid >> 5, g = (tid >> 2) & 7, o = tid & 3;

    // load this (px,g)'s packed offsets+mask logits: 4x16B
    const ushortT* omp = omb + (size_t)(base + px) * 256 + g * 32;
    const u32x4 L0 = *(const u32x4*)(omp);        // opairs p0-3
    const u32x4 L1 = *(const u32x4*)(omp + 8);    // opairs p4-7
    const u32x4 L2 = *(const u32x4*)(omp + 16);   // opair p8, logits p0-5
    const u32x4 L3 = *(const u32x4*)(omp + 24);   // logits p6-8
    unsigned opair[9];
    #pragma unroll
    for (int p = 0; p < 4; ++p) { opair[p] = L0[p]; opair[4 + p] = L1[p]; }
    opair[8] = L2[0];
    float lg[9];
    lg[0] = bflo(L2[1]); lg[1] = bfhi(L2[1]);
    lg[2] = bflo(L2[2]); lg[3] = bfhi(L2[2]);
    lg[4] = bflo(L2[3]); lg[5] = bfhi(L2[3]);
    lg[6] = bflo(L3[0]); lg[7] = bfhi(L3[0]);
    lg[8] = bflo(L3[1]);
    float mx = -1e30f;
    #pragma unroll
    for (int p = 0; p < 9; ++p) mx = fmaxf(mx, lg[p]);
    float sum = 0.f;
    #pragma unroll
    for (int p = 0; p < 9; ++p) sum += __expf(lg[p] - mx);
    const float inv = __builtin_amdgcn_rcpf(sum);

    const ushortT* xn = xpb + (size_t)n * (4096 * 256) + g * 32 + o * 8;
    float acc[8];
    #pragma unroll
    for (int j = 0; j < 8; ++j) acc[j] = 0.f;

    #pragma unroll
    for (int p = 0; p < 9; ++p) {
        const float m = __expf(lg[p] - mx) * inv;
        const float ox = bflo(opair[p]), oy = bfhi(opair[p]);
        const float pxc = (float)(w0 + px + p / 3) + ox;   // padded coords
        const float pyc = (float)(h + p % 3) + oy;
        const float xf = floorf(pxc), yf = floorf(pyc);
        const float tx = pxc - xf, ty = pyc - yf;
        const int x0 = (int)xf - 1, y0 = (int)yf - 1;      // unpadded
        const int x1 = x0 + 1, y1 = y0 + 1;
        const float wx0 = ((unsigned)x0 < 64u) ? (1.f - tx) : 0.f;
        const float wx1 = ((unsigned)x1 < 64u) ? tx : 0.f;
        const float wy0 = ((unsigned)y0 < 64u) ? (1.f - ty) : 0.f;
        const float wy1 = ((unsigned)y1 < 64u) ? ty : 0.f;
        const int cx0 = min(max(x0, 0), 63), cx1 = min(max(x1, 0), 63);
        const int cy0 = min(max(y0, 0), 63), cy1 = min(max(y1, 0), 63);
        const int o00 = (cy0 * 64 + cx0) * 256;
        const int o10 = (cy0 * 64 + cx1) * 256;
        const int o01 = (cy1 * 64 + cx0) * 256;
        const int o11 = (cy1 * 64 + cx1) * 256;
        const float w00 = m * wx0 * wy0, w10 = m * wx1 * wy0;
        const float w01 = m * wx0 * wy1, w11 = m * wx1 * wy1;
        const u32x4 A = *(const u32x4*)(xn + o00);
        const u32x4 B = *(const u32x4*)(xn + o10);
        const u32x4 C = *(const u32x4*)(xn + o01);
        const u32x4 D = *(const u32x4*)(xn + o11);
        #pragma unroll
        for (int i = 0; i < 4; ++i) {
            acc[2 * i]     += w00 * bflo(A[i]) + w10 * bflo(B[i])
                            + w01 * bflo(C[i]) + w11 * bflo(D[i]);
            acc[2 * i + 1] += w00 * bfhi(A[i]) + w10 * bfhi(B[i])
                            + w01 * bfhi(C[i]) + w11 * bfhi(D[i]);
        }
    }
    u16x8 cv;
    #pragma unroll
    for (int j = 0; j < 8; ++j) cv[j] = f2bf(acc[j]);
    *(u16x8*)(coreb + (size_t)(base + px) * 256 + g * 32 + o * 8) = cv;
}

// ---------------- k_gemm_out: out = core @ W_out^T + b_out ----------------
// 32-row tile, 512 threads / 8 waves. LDS swizzle chunk ^= row&15.
__global__ __launch_bounds__(512) void k_gemm_out(
    const ushortT* __restrict__ A, const ushortT* __restrict__ Bt,
    const float* __restrict__ bias, float* __restrict__ out)
{
    __shared__ __align__(16) ushortT As[32 * 256];
    const int tid = threadIdx.x;
    const int m0 = blockIdx.x * 32;
    const int lane = tid & 63, wave = tid >> 6;

    #pragma unroll
    for (int it = 0; it < 2; ++it) {
        const int i = it * 512 + tid;
        const int row = i >> 5, ch = i & 31;
        const int sch = ch ^ (row & 15);
        gload_lds16(A + (size_t)(m0 + row) * 256 + sch * 8, (char*)As + i * 16);
    }
    bf16x8 bbp[2];
    #pragma unroll
    for (int nn = 0; nn < 2; ++nn) {
        const int ncol = wave * 32 + nn * 16 + (lane & 15);
        bbp[nn] = *(const bf16x8*)(Bt + (size_t)ncol * 256 + (lane >> 4) * 8);
    }
    asm volatile("s_waitcnt vmcnt(0)");
    __syncthreads();

    f32x4 acc[2][2];
    #pragma unroll
    for (int m = 0; m < 2; ++m)
        #pragma unroll
        for (int nn = 0; nn < 2; ++nn) acc[m][nn] = (f32x4){0.f, 0.f, 0.f, 0.f};

    #pragma unroll
    for (int k0 = 0; k0 < 256; k0 += 32) {
        bf16x8 af[2], bb[2];
        #pragma unroll
        for (int nn = 0; nn < 2; ++nn) bb[nn] = bbp[nn];
        if (k0 + 32 < 256) {
            #pragma unroll
            for (int nn = 0; nn < 2; ++nn) {
                const int ncol = wave * 32 + nn * 16 + (lane & 15);
                bbp[nn] = *(const bf16x8*)(Bt + (size_t)ncol * 256 + (k0 + 32) + (lane >> 4) * 8);
            }
        }
        #pragma unroll
        for (int m = 0; m < 2; ++m) {
            const int row = m * 16 + (lane & 15);
            af[m] = *(const bf16x8*)((const char*)As + row * 512 +
                     (((k0 + (lane >> 4) * 8) * 2) ^ ((row & 15) << 4)));
        }
        #pragma unroll
        for (int m = 0; m < 2; ++m)
            #pragma unroll
            for (int nn = 0; nn < 2; ++nn)
                acc[m][nn] = __builtin_amdgcn_mfma_f32_16x16x32_bf16(af[m], bb[nn], acc[m][nn], 0, 0, 0);
    }

    const int rbase = (lane >> 4) * 4, col16 = lane & 15;
    #pragma unroll
    for (int m = 0; m < 2; ++m) {
        #pragma unroll
        for (int nn = 0; nn < 2; ++nn) {
            const int col = wave * 32 + nn * 16 + col16;
            const float bj = bias[col];
            #pragma unroll
            for (int r = 0; r < 4; ++r) {
                const int row = m0 + m * 16 + rbase + r;
                out[(size_t)row * 256 + col] = acc[m][nn][r] + bj;
            }
        }
    }
}

extern "C" void kernel_launch(void* const* d_in, const int* in_sizes, int n_in,
                              void* d_out, int out_size, void* d_ws, size_t ws_size,
                              hipStream_t stream) {
    const float* x        = (const float*)d_in[0];
    const float* dw_w     = (const float*)d_in[1];
    const float* bn_gamma = (const float*)d_in[2];
    const float* bn_beta  = (const float*)d_in[3];
    const float* bn_mean  = (const float*)d_in[4];
    const float* bn_var   = (const float*)d_in[5];
    const float* W_off    = (const float*)d_in[6];
    const float* b_off    = (const float*)d_in[7];
    const float* W_mask   = (const float*)d_in[8];
    const float* b_mask   = (const float*)d_in[9];
    const float* W_in     = (const float*)d_in[10];
    const float* b_in     = (const float*)d_in[11];
    const float* W_out    = (const float*)d_in[12];
    const float* b_out    = (const float*)d_in[13];
    float* out = (float*)d_out;

    char* w = (char*)d_ws;
    ushortT* Wt    = (ushortT*)w;                        // 393216 B
    float* biasb   = (float*)(w + 393216);               // 3072 B
    ushortT* xpb   = (ushortT*)(w + 396288);             // 8 MB bf16 xproj
    ushortT* omb   = (ushortT*)(w + 396288 + 8388608);   // 8 MB bf16 offsets+mask (permuted)
    ushortT* coreb = (ushortT*)(w + 396288 + 2 * 8388608); // 8 MB

    hipLaunchKernelGGL(k_wt, dim3(768), dim3(256), 0, stream,
                       W_in, W_out, W_off, W_mask, b_in, b_out, b_off, b_mask, Wt, biasb);
    hipLaunchKernelGGL(k_fused_in, dim3(512), dim3(512), 0, stream,
                       x, dw_w, bn_gamma, bn_beta, bn_mean, bn_var, Wt, biasb, xpb, omb);
    hipLaunchKernelGGL(k_core, dim3(2048), dim3(256), 0, stream,
                       omb, xpb, coreb);
    hipLaunchKernelGGL(k_gemm_out, dim3(NPIX / 32), dim3(512), 0, stream,
                       coreb, Wt + 65536, biasb + 256, out);
}